// Round 16
// baseline (173.348 us; speedup 1.0000x reference)
//
#include <hip/hip_runtime.h>
#include <hip/hip_bf16.h>

// ---------------------------------------------------------------------------
// CollapsedPBFA: x->(qkv GEMM)->cheb-kernelized linear attention->out GEMM
// R16: both GEMMs ported to the exact m97 structure (128x128 tile, BK=32,
//      4 waves, single-buffer 2-barrier K-loop, gload16 staging, linear
//      [128][32] LDS, 16KB -> ~3 blocks/CU). gemm2 gains 2-blocks/CU
//      co-residency (512 blocks). Rest identical to R15 (best, 156.6us).
//      absmax tripwire: 32.0.
// ---------------------------------------------------------------------------

#define SEQ    4096
#define BATCH  2
#define DMODEL 1024
#define NH     16
#define DH     64
#define MD     11
#define NCH    8
#define CHUNK  512   // SEQ / NCH

typedef __attribute__((ext_vector_type(8)))  short  short8;
typedef __attribute__((ext_vector_type(4)))  short  s16x4;
typedef __attribute__((ext_vector_type(8)))  __bf16 bf16x8;
typedef __attribute__((ext_vector_type(4)))  float  f32x4;

__device__ __forceinline__ short f2bf(float f) {
  union { float f; unsigned u; } c; c.f = f;
  unsigned r = c.u + 0x7FFFu + ((c.u >> 16) & 1u);
  return (short)(r >> 16);
}
__device__ __forceinline__ float bf2f(short h) {
  union { unsigned u; float f; } c; c.u = ((unsigned)(unsigned short)h) << 16;
  return c.f;
}

__device__ __forceinline__ f32x4 mfma16(short8 a, short8 b, f32x4 c) {
  return __builtin_amdgcn_mfma_f32_16x16x32_bf16(
      __builtin_bit_cast(bf16x8, a), __builtin_bit_cast(bf16x8, b), c, 0, 0, 0);
}

typedef const __attribute__((address_space(1))) void* gvp;
typedef __attribute__((address_space(3))) void* lvp;
__device__ __forceinline__ void gload16(const void* g, void* l) {
  __builtin_amdgcn_global_load_lds((gvp)g, (lvp)l, 16, 0, 0);
}

// ---------------------------------------------------------------------------
// fused f32 -> bf16 convert for x, w_in, w_out in one launch (12288 blocks).
// ---------------------------------------------------------------------------
__global__ __launch_bounds__(256) void to_bf16_all(const float* __restrict__ x,
                                                   const float* __restrict__ w_in,
                                                   const float* __restrict__ w_out,
                                                   short* __restrict__ xb,
                                                   short* __restrict__ w_inb,
                                                   short* __restrict__ w_outb) {
  int i = blockIdx.x * 256 + threadIdx.x;
  const float* src; short* dst; int off;
  if (i < 2097152)      { src = x;     dst = xb;     off = i; }
  else if (i < 2883584) { src = w_in;  dst = w_inb;  off = i - 2097152; }
  else                  { src = w_out; dst = w_outb; off = i - 2883584; }
  f32x4 v = ((const f32x4*)src)[off];
  s16x4 o;
#pragma unroll
  for (int q = 0; q < 4; ++q) o[q] = f2bf(v[q]);
  ((s16x4*)dst)[off] = o;
}

// ---------------------------------------------------------------------------
// GEMM (m97 structure): C[M][N] = A[M][K] * B[N][K]^T, bf16 in.
// 128x128 tile, BK=32, 256 threads = 4 waves (wr=w>>1, wc=w&1, each 64x64),
// single-buffer LDS (16KB), 2 barriers per K-step, gload16 staging.
// LAYOUT 0: row-major C[row][col] (type SC).
// LAYOUT 1: head-major bf16: C[(col>>6)][row][col&63], slab stride 8192*64.
// Requires: M%128==0, N%128==0, K%32==0, grid%8==0.
// ---------------------------------------------------------------------------
template <typename SC, int LAYOUT>
__global__ __launch_bounds__(256) void gemm128(const short* __restrict__ A,
                                               const short* __restrict__ B,
                                               SC* __restrict__ C,
                                               int M, int N, int K) {
  __shared__ short aT[128 * 32];
  __shared__ short bT[128 * 32];

  const int tid  = threadIdx.x;
  const int lane = tid & 63;
  const int w    = tid >> 6;    // 0..3
  const int wr   = w >> 1;      // 0..1
  const int wc   = w & 1;       // 0..1
  const int g    = lane >> 4;   // 0..3
  const int r    = lane & 15;   // 0..15

  const int nbn = N >> 7;
  int bid = blockIdx.x;
  {  // bijective XCD swizzle (gridDim.x % 8 == 0 for our shapes)
    const int cpx = gridDim.x >> 3;
    bid = (bid & 7) * cpx + (bid >> 3);
  }
  const int brow = (bid / nbn) << 7;
  const int bcol = (bid % nbn) << 7;

  // staging lane geometry: per issue a wave covers 16 rows x 32 cols.
  const int lr = lane >> 2;        // 0..15 row within issue
  const int lc = (lane & 3) * 8;   // 16B chunk within row (shorts)

  f32x4 acc[4][4];
#pragma unroll
  for (int mi = 0; mi < 4; ++mi)
#pragma unroll
    for (int ni = 0; ni < 4; ++ni) acc[mi][ni] = (f32x4){0.f, 0.f, 0.f, 0.f};

  const short* gA = A + (size_t)(brow + w * 32 + lr) * K + lc;
  const short* gB = B + (size_t)(bcol + w * 32 + lr) * K + lc;

  for (int k0 = 0; k0 < K; k0 += 32) {
    __syncthreads();
    gload16(gA + k0,                 &aT[(w * 32) * 32]);
    gload16(gA + k0 + (size_t)16 * K, &aT[(w * 32 + 16) * 32]);
    gload16(gB + k0,                 &bT[(w * 32) * 32]);
    gload16(gB + k0 + (size_t)16 * K, &bT[(w * 32 + 16) * 32]);
    __syncthreads();   // drains vmcnt(0): staged data visible

    short8 av[4], bv[4];
#pragma unroll
    for (int mi = 0; mi < 4; ++mi)
      av[mi] = *(const short8*)&aT[(wr * 64 + mi * 16 + r) * 32 + g * 8];
#pragma unroll
    for (int ni = 0; ni < 4; ++ni)
      bv[ni] = *(const short8*)&bT[(wc * 64 + ni * 16 + r) * 32 + g * 8];

#pragma unroll
    for (int mi = 0; mi < 4; ++mi)
#pragma unroll
      for (int ni = 0; ni < 4; ++ni)
        acc[mi][ni] = mfma16(av[mi], bv[ni], acc[mi][ni]);
  }

#pragma unroll
  for (int mi = 0; mi < 4; ++mi) {
    const int row0 = brow + wr * 64 + mi * 16 + g * 4;
#pragma unroll
    for (int ni = 0; ni < 4; ++ni) {
      const int col = bcol + wc * 64 + ni * 16 + r;
#pragma unroll
      for (int rr = 0; rr < 4; ++rr) {
        float v = acc[mi][ni][rr];
        if constexpr (LAYOUT == 1) {
          short* dst = (short*)C + (((size_t)(col >> 6)) << 19) +
                       (size_t)(row0 + rr) * 64 + (col & 63);
          *dst = f2bf(v);
        } else if constexpr (sizeof(SC) == 2) {
          C[(size_t)(row0 + rr) * N + col] = f2bf(v);
        } else {
          C[(size_t)(row0 + rr) * N + col] = v;
        }
      }
    }
  }
}

// ---------------------------------------------------------------------------
// kv partial: block = (bh, chunk of 512 s-rows). Head-major k/v source ->
// dense coalesced staging. Partials written transposed [dv][kd] bf16.
// ---------------------------------------------------------------------------
__global__ __launch_bounds__(256) void kv_partial(const short* __restrict__ qkv,
                                                  const float* __restrict__ beta,
                                                  short* __restrict__ partial) {
  const int bh = blockIdx.x / NCH;
  const int ch = blockIdx.x % NCH;
  const int b  = bh >> 4, h = bh & 15;

  __shared__ short kT[64][522];   // [kd][s], stride 261 dw
  __shared__ short vT[64][522];   // [dv][s]

  const int tid  = threadIdx.x;
  const int lane = tid & 63;
  const int w    = tid >> 6;
  const int g    = lane >> 4;
  const int r    = lane & 15;

  const int srl  = tid >> 2;   // 0..63 (row)
  const int part = tid & 3;    // 0..3  (16-short chunk)
  const size_t rbase = (size_t)(b * 4096 + ch * CHUNK);
  const short* kbase = qkv + (((size_t)(16 + h)) << 19) + rbase * 64 + part * 16;
  const short* vbase = qkv + (((size_t)(32 + h)) << 19) + rbase * 64 + part * 16;

#pragma unroll
  for (int ss = 0; ss < CHUNK; ss += 64) {
    const short* gk = kbase + (size_t)(ss + srl) * 64;
    const short* gv = vbase + (size_t)(ss + srl) * 64;
    short8 k0 = *(const short8*)gk;
    short8 k1 = *(const short8*)(gk + 8);
    short8 v0 = *(const short8*)gv;
    short8 v1 = *(const short8*)(gv + 8);
    const int sidx = ss + srl;
#pragma unroll
    for (int q = 0; q < 8; ++q) {
      kT[part * 16 + q][sidx]     = f2bf(fminf(fmaxf(bf2f(k0[q]) * 0.125f, -1.f), 1.f));
      kT[part * 16 + 8 + q][sidx] = f2bf(fminf(fmaxf(bf2f(k1[q]) * 0.125f, -1.f), 1.f));
      vT[part * 16 + q][sidx]     = v0[q];
      vT[part * 16 + 8 + q][sidx] = v1[q];
    }
  }
  __syncthreads();

  for (int m = 0; m < MD; ++m) {
    if (beta[h * MD + m] == 0.f) continue;

    f32x4 acc[4];
#pragma unroll
    for (int j = 0; j < 4; ++j) acc[j] = (f32x4){0.f, 0.f, 0.f, 0.f};

#pragma unroll 1
    for (int kt = 0; kt < CHUNK / 32; ++kt) {
      const int s0 = kt * 32 + g * 8;
      short8 af;
      if (m == 0) {
#pragma unroll
        for (int q = 0; q < 8; ++q) af[q] = (short)0x3F80;
      } else {
        short8 xs = *(const short8*)&kT[w * 16 + r][s0];
        float Tp[8], Tc[8];
#pragma unroll
        for (int q = 0; q < 8; ++q) { float xv = bf2f(xs[q]); Tp[q] = 1.f; Tc[q] = xv; }
        for (int mm = 1; mm < m; ++mm) {
#pragma unroll
          for (int q = 0; q < 8; ++q) {
            float xv = bf2f(xs[q]);
            float Tn = 2.f * xv * Tc[q] - Tp[q];
            Tp[q] = Tc[q]; Tc[q] = Tn;
          }
        }
#pragma unroll
        for (int q = 0; q < 8; ++q) af[q] = f2bf(Tc[q]);
      }
#pragma unroll
      for (int j = 0; j < 4; ++j) {
        short8 bfg = *(const short8*)&vT[j * 16 + r][s0];
        acc[j] = mfma16(af, bfg, acc[j]);
      }
    }

    short* po = partial + ((size_t)(bh * MD + m) * NCH + ch) * 4096;
#pragma unroll
    for (int j = 0; j < 4; ++j) {
      const int dv = j * 16 + r;
      const int kd = w * 16 + g * 4;
#pragma unroll
      for (int rr = 0; rr < 4; ++rr) po[(size_t)dv * 64 + kd + rr] = f2bf(acc[j][rr]);
    }
  }
}

// ---------------------------------------------------------------------------
// reduce partials (flat, coalesced) -> kvt bf16 [bh][m][dv*64+kd].
// ---------------------------------------------------------------------------
__global__ __launch_bounds__(256) void kv_reduce(const short* __restrict__ partial,
                                                 const float* __restrict__ beta,
                                                 short* __restrict__ kvt) {
  const int m  = blockIdx.x % MD;
  const int bh = blockIdx.x / MD;
  const int h  = bh & 15;
  if (beta[h * MD + m] == 0.f) return;

  const int t = threadIdx.x;
  const short* src = partial + (size_t)(bh * MD + m) * NCH * 4096;
  short* dst = kvt + (size_t)(bh * MD + m) * 4096;

  float s[16];
#pragma unroll
  for (int q = 0; q < 16; ++q) s[q] = 0.f;
#pragma unroll
  for (int c = 0; c < NCH; ++c) {
    short8 a0 = *(const short8*)&src[c * 4096 + t * 16];
    short8 a1 = *(const short8*)&src[c * 4096 + t * 16 + 8];
#pragma unroll
    for (int q = 0; q < 8; ++q) { s[q] += bf2f(a0[q]); s[8 + q] += bf2f(a1[q]); }
  }
  short8 o0, o1;
#pragma unroll
  for (int q = 0; q < 8; ++q) { o0[q] = f2bf(s[q]); o1[q] = f2bf(s[8 + q]); }
  *(short8*)&dst[t * 16]     = o0;
  *(short8*)&dst[t * 16 + 8] = o1;
}

// ---------------------------------------------------------------------------
// attn: per (b,h,256 s-rows). 8-slot kv LDS (66.5KB -> 2 blocks/CU), R14
// loop structure (stage-once, st-outer, per-st acc[4]). Groups of 8 slots;
// groups past the first accumulate through the attn buffer (dead code for
// the real beta: na=5 -> single group).
// ---------------------------------------------------------------------------
__global__ __launch_bounds__(256) void attn_kernel(const short* __restrict__ qkv,
                                                   const float* __restrict__ beta,
                                                   const short* __restrict__ kvt,
                                                   short* __restrict__ attn) {
  const int bid  = blockIdx.x;
  const int bh   = bid >> 4;
  const int sblk = bid & 15;
  const int b    = bh >> 4, h = bh & 15;

  __shared__ short kvT[64][520];   // 8 slots x 64 + 8 pad; 66,560 B

  const int tid  = threadIdx.x;
  const int lane = tid & 63;
  const int w    = tid >> 6;
  const int g    = lane >> 4;
  const int r    = lane & 15;

  float betav[MD];
  int na = 0;
#pragma unroll
  for (int mm = 0; mm < MD; ++mm) {
    betav[mm] = beta[h * MD + mm];
    if (betav[mm] != 0.f) ++na;
  }

  const short* qh = qkv + (((size_t)h) << 19) + (size_t)(b * 4096) * 64;

#pragma unroll 1
  for (int g0 = 0; g0 < na; g0 += 8) {
    if (g0 > 0) __syncthreads();
    // ---- stage this group's kv slices (vectorized, flat) ----
    {
      const int dv  = tid >> 2;
      const int kd0 = (tid & 3) * 16;
      int ord = 0;
#pragma unroll
      for (int mm = 0; mm < MD; ++mm) {
        if (betav[mm] != 0.f) {
          if (ord >= g0 && ord < g0 + 8) {
            const int slot = ord - g0;
            const short* src = kvt + (size_t)(bh * MD + mm) * 4096 + dv * 64 + kd0;
            *(short8*)&kvT[dv][slot * 64 + kd0]     = *(const short8*)src;
            *(short8*)&kvT[dv][slot * 64 + kd0 + 8] = *(const short8*)(src + 8);
          }
          ++ord;
        }
      }
    }
    __syncthreads();

#pragma unroll 1
    for (int st = 0; st < 4; ++st) {
      const int srow = sblk * 256 + w * 64 + st * 16 + r;
      const short* gq = qh + (size_t)srow * 64;
      short8 q0 = *(const short8*)(gq + g * 8);
      short8 q1 = *(const short8*)(gq + 32 + g * 8);
      float x[16];
#pragma unroll
      for (int q = 0; q < 8; ++q) {
        x[q]     = fminf(fmaxf(bf2f(q0[q]) * 0.125f, -1.f), 1.f);
        x[8 + q] = fminf(fmaxf(bf2f(q1[q]) * 0.125f, -1.f), 1.f);
      }
      float Tp[16], Tc[16];
#pragma unroll
      for (int q = 0; q < 16; ++q) { Tp[q] = 1.f; Tc[q] = x[q]; }
      f32x4 acc[4];
#pragma unroll
      for (int j = 0; j < 4; ++j) acc[j] = (f32x4){0.f, 0.f, 0.f, 0.f};

      int ord = 0;
#pragma unroll
      for (int mt = 0; mt < MD; ++mt) {
        if (mt >= 2) {
#pragma unroll
          for (int q = 0; q < 16; ++q) {
            float Tn = 2.f * x[q] * Tc[q] - Tp[q];
            Tp[q] = Tc[q]; Tc[q] = Tn;
          }
        }
        if (betav[mt] != 0.f) {
          if (ord >= g0 && ord < g0 + 8) {
            const int slot = ord - g0;
            const float bm = betav[mt];
            short8 a0, a1;
            if (mt == 0) {
              const short one = f2bf(bm);
#pragma unroll
              for (int q = 0; q < 8; ++q) { a0[q] = one; a1[q] = one; }
            } else {
#pragma unroll
              for (int q = 0; q < 8; ++q) {
                a0[q] = f2bf(bm * Tc[q]);
                a1[q] = f2bf(bm * Tc[8 + q]);
              }
            }
#pragma unroll
            for (int j = 0; j < 4; ++j) {
              short8 b0 = *(const short8*)&kvT[j * 16 + r][slot * 64 + g * 8];
              acc[j] = mfma16(a0, b0, acc[j]);
              short8 b1 = *(const short8*)&kvT[j * 16 + r][slot * 64 + 32 + g * 8];
              acc[j] = mfma16(a1, b1, acc[j]);
            }
          }
          ++ord;
        }
      }

#pragma unroll
      for (int j = 0; j < 4; ++j) {
        const int col = h * 64 + j * 16 + r;
#pragma unroll
        for (int rr = 0; rr < 4; ++rr) {
          const int sr = sblk * 256 + w * 64 + st * 16 + g * 4 + rr;
          short* dp = attn + (size_t)(b * SEQ + sr) * DMODEL + col;
          float v = acc[j][rr];
          if (g0 > 0) v += bf2f(*dp);   // dead for real beta (na=5)
          *dp = f2bf(v);
        }
      }
    }
  }
}

// ---------------------------------------------------------------------------
extern "C" void kernel_launch(void* const* d_in, const int* in_sizes, int n_in,
                              void* d_out, int out_size, void* d_ws, size_t ws_size,
                              hipStream_t stream) {
  const float* x     = (const float*)d_in[0];
  const float* w_in  = (const float*)d_in[1];
  const float* w_out = (const float*)d_in[2];
  const float* beta  = (const float*)d_in[3];
  float* out = (float*)d_out;

  char* ws = (char*)d_ws;
  short* qkv     = (short*)ws;                    // 50,331,648 B (head-major)
  short* kvt     = (short*)(ws + 50331648);       //  2,883,584 B
  short* w_inb   = (short*)(ws + 56098816);       //  6,291,456 B
  short* w_outb  = (short*)(ws + 62390272);       //  2,097,152 B
  char*  regionU = ws + 64487424;                 // xb / partial / attn union
  short* xb      = (short*)regionU;
  short* partial = (short*)regionU;
  short* attn    = (short*)regionU;

  const int Mrows = BATCH * SEQ;  // 8192

  // 0) pre-convert f32 -> bf16 (single fused launch)
  to_bf16_all<<<dim3(12288), dim3(256), 0, stream>>>(x, w_in, w_out, xb, w_inb, w_outb);

  // 1) qkv = x @ w_in^T (head-major out): 64 x 24 = 1536 blocks (128x128)
  gemm128<short, 1><<<dim3((Mrows / 128) * (3 * DMODEL / 128)), dim3(256), 0, stream>>>(
      xb, w_inb, qkv, Mrows, 3 * DMODEL, DMODEL);

  // 2) kv partials over s-chunks, then flat reduce -> kvt
  kv_partial<<<dim3(BATCH * NH * NCH), dim3(256), 0, stream>>>(qkv, beta, partial);
  kv_reduce<<<dim3(BATCH * NH * MD), dim3(256), 0, stream>>>(partial, beta, kvt);

  // 3) attn = sum_m beta_m T_m(q) @ kv_m
  attn_kernel<<<dim3(32 * 16), dim3(256), 0, stream>>>(qkv, beta, kvt, attn);

  // 4) out = attn @ w_out^T: 64 x 8 = 512 blocks (128x128)
  gemm128<float, 0><<<dim3((Mrows / 128) * (DMODEL / 128)), dim3(256), 0, stream>>>(
      attn, w_outb, out, Mrows, DMODEL, DMODEL);
}

// Round 17
// 156.059 us; speedup vs baseline: 1.1108x; 1.1108x over previous
//
#include <hip/hip_runtime.h>
#include <hip/hip_bf16.h>

// ---------------------------------------------------------------------------
// CollapsedPBFA: x->(qkv GEMM)->cheb-kernelized linear attention->out GEMM
// R17: exact revert to R15 (measured best, 156.6us). R16's m97-structure
//      GEMM regressed (654 vs 805 TF at K=1024: 2-barrier single-buffer
//      doesn't amortize at 32 K-steps). GEMM family closed.
//      absmax tripwire: 32.0.
// ---------------------------------------------------------------------------

#define SEQ    4096
#define BATCH  2
#define DMODEL 1024
#define NH     16
#define DH     64
#define MD     11
#define NCH    8
#define CHUNK  512   // SEQ / NCH

typedef __attribute__((ext_vector_type(8)))  short  short8;
typedef __attribute__((ext_vector_type(4)))  short  s16x4;
typedef __attribute__((ext_vector_type(8)))  __bf16 bf16x8;
typedef __attribute__((ext_vector_type(4)))  float  f32x4;

__device__ __forceinline__ short f2bf(float f) {
  union { float f; unsigned u; } c; c.f = f;
  unsigned r = c.u + 0x7FFFu + ((c.u >> 16) & 1u);
  return (short)(r >> 16);
}
__device__ __forceinline__ float bf2f(short h) {
  union { unsigned u; float f; } c; c.u = ((unsigned)(unsigned short)h) << 16;
  return c.f;
}

__device__ __forceinline__ f32x4 mfma16(short8 a, short8 b, f32x4 c) {
  return __builtin_amdgcn_mfma_f32_16x16x32_bf16(
      __builtin_bit_cast(bf16x8, a), __builtin_bit_cast(bf16x8, b), c, 0, 0, 0);
}

typedef const __attribute__((address_space(1))) void* gvp;
typedef __attribute__((address_space(3))) void* lvp;
// Async global->LDS, 16B per lane: lane i lands at (uniform dst) + 16*i.
__device__ __forceinline__ void gload16(const void* g, void* l) {
  __builtin_amdgcn_global_load_lds((gvp)g, (lvp)l, 16, 0, 0);
}

// ---------------------------------------------------------------------------
// fused f32 -> bf16 convert for x, w_in, w_out in one launch (12288 blocks).
// ---------------------------------------------------------------------------
__global__ __launch_bounds__(256) void to_bf16_all(const float* __restrict__ x,
                                                   const float* __restrict__ w_in,
                                                   const float* __restrict__ w_out,
                                                   short* __restrict__ xb,
                                                   short* __restrict__ w_inb,
                                                   short* __restrict__ w_outb) {
  int i = blockIdx.x * 256 + threadIdx.x;
  const float* src; short* dst; int off;
  if (i < 2097152)      { src = x;     dst = xb;     off = i; }
  else if (i < 2883584) { src = w_in;  dst = w_inb;  off = i - 2097152; }
  else                  { src = w_out; dst = w_outb; off = i - 2883584; }
  f32x4 v = ((const f32x4*)src)[off];
  s16x4 o;
#pragma unroll
  for (int q = 0; q < 4; ++q) o[q] = f2bf(v[q]);
  ((s16x4*)dst)[off] = o;
}

// ---------------------------------------------------------------------------
// GEMM (R8 structure, best measured): C[M][N] = A[M][K] * B[N][K]^T, bf16 in.
// Tile 256x128, BK=32, 8 waves, 3-buf LDS (72KB -> 2 blocks/CU), distance-2
// staging, vmcnt(3)+1 barrier per tile.
// LAYOUT 0: row-major C[row][col] (type SC).
// LAYOUT 1: head-major bf16: C[(col>>6)][row][col&63], slab stride 8192*64.
// ---------------------------------------------------------------------------
template <typename SC, int LAYOUT>
__global__ __launch_bounds__(512, 4) void gemm256(const short* __restrict__ A,
                                                  const short* __restrict__ B,
                                                  SC* __restrict__ C,
                                                  int M, int N, int K) {
  __shared__ short lds[36864];

  const int tid  = threadIdx.x;
  const int lane = tid & 63;
  const int w    = tid >> 6;        // 0..7
  const int wm   = w >> 1;          // 0..3
  const int wn   = w & 1;           // 0..1
  const int g    = lane >> 4;       // 0..3
  const int r    = lane & 15;       // 0..15

  const int nbn = N >> 7;
  int bid = blockIdx.x;
  {
    const int cpx = gridDim.x >> 3;
    bid = (bid & 7) * cpx + (bid >> 3);
  }
  const int brow = (bid / nbn) << 8;
  const int bcol = (bid % nbn) << 7;
  const int NT   = K >> 5;

  const int lr = lane >> 2;
  const int lc = (lane & 3) * 8;

  f32x4 acc[4][4];
#pragma unroll
  for (int mi = 0; mi < 4; ++mi)
#pragma unroll
    for (int ni = 0; ni < 4; ++ni) acc[mi][ni] = (f32x4){0.f, 0.f, 0.f, 0.f};

  const short* gA0 = A + (size_t)(brow + 0   + w * 16 + lr) * K + lc;
  const short* gA1 = A + (size_t)(brow + 128 + w * 16 + lr) * K + lc;
  const short* gB0 = B + (size_t)(bcol +       w * 16 + lr) * K + lc;

  auto STAGE = [&](int buf, int t) {
    const int k0 = t << 5;
    short* ab = &lds[buf * 12288];
    short* bb = &lds[buf * 12288 + 8192];
    gload16(gA0 + k0, ab + (w * 16) * 32);
    gload16(gA1 + k0, ab + (128 + w * 16) * 32);
    gload16(gB0 + k0, bb + (w * 16) * 32);
  };

  STAGE(0, 0);
  STAGE(1, 1);
  asm volatile("s_waitcnt vmcnt(3)\n\ts_barrier" ::: "memory");

  for (int kt = 0; kt < NT; ++kt) {
    const int cur = kt % 3;
    const short* ab = &lds[cur * 12288];
    const short* bb = &lds[cur * 12288 + 8192];

    if (kt + 2 < NT) STAGE((kt + 2) % 3, kt + 2);

    short8 av[4], bv[4];
#pragma unroll
    for (int mi = 0; mi < 4; ++mi)
      av[mi] = *(const short8*)(ab + (wm * 64 + mi * 16 + r) * 32 + g * 8);
#pragma unroll
    for (int ni = 0; ni < 2; ++ni)
      bv[ni] = *(const short8*)(bb + (wn * 64 + ni * 16 + r) * 32 + g * 8);

    __builtin_amdgcn_s_setprio(1);
#pragma unroll
    for (int mi = 0; mi < 4; ++mi)
#pragma unroll
      for (int ni = 0; ni < 2; ++ni)
        acc[mi][ni] = mfma16(av[mi], bv[ni], acc[mi][ni]);
    __builtin_amdgcn_s_setprio(0);

#pragma unroll
    for (int ni = 2; ni < 4; ++ni)
      bv[ni] = *(const short8*)(bb + (wn * 64 + ni * 16 + r) * 32 + g * 8);

    __builtin_amdgcn_s_setprio(1);
#pragma unroll
    for (int mi = 0; mi < 4; ++mi)
#pragma unroll
      for (int ni = 2; ni < 4; ++ni)
        acc[mi][ni] = mfma16(av[mi], bv[ni], acc[mi][ni]);
    __builtin_amdgcn_s_setprio(0);

    if (kt + 1 < NT) {
      if (kt + 2 < NT) asm volatile("s_waitcnt vmcnt(3)\n\ts_barrier" ::: "memory");
      else             asm volatile("s_waitcnt vmcnt(0)\n\ts_barrier" ::: "memory");
    }
  }

#pragma unroll
  for (int mi = 0; mi < 4; ++mi) {
    const int row0 = brow + wm * 64 + mi * 16 + g * 4;
#pragma unroll
    for (int ni = 0; ni < 4; ++ni) {
      const int col = bcol + wn * 64 + ni * 16 + r;
#pragma unroll
      for (int rr = 0; rr < 4; ++rr) {
        float v = acc[mi][ni][rr];
        if constexpr (LAYOUT == 1) {
          short* dst = (short*)C + (((size_t)(col >> 6)) << 19) +
                       (size_t)(row0 + rr) * 64 + (col & 63);
          *dst = f2bf(v);
        } else if constexpr (sizeof(SC) == 2) {
          C[(size_t)(row0 + rr) * N + col] = f2bf(v);
        } else {
          C[(size_t)(row0 + rr) * N + col] = v;
        }
      }
    }
  }
}

// ---------------------------------------------------------------------------
// kv partial: block = (bh, chunk of 512 s-rows). Head-major k/v source ->
// dense coalesced staging. Partials written transposed [dv][kd] bf16.
// ---------------------------------------------------------------------------
__global__ __launch_bounds__(256) void kv_partial(const short* __restrict__ qkv,
                                                  const float* __restrict__ beta,
                                                  short* __restrict__ partial) {
  const int bh = blockIdx.x / NCH;
  const int ch = blockIdx.x % NCH;
  const int b  = bh >> 4, h = bh & 15;

  __shared__ short kT[64][522];   // [kd][s], stride 261 dw
  __shared__ short vT[64][522];   // [dv][s]

  const int tid  = threadIdx.x;
  const int lane = tid & 63;
  const int w    = tid >> 6;
  const int g    = lane >> 4;
  const int r    = lane & 15;

  const int srl  = tid >> 2;   // 0..63 (row)
  const int part = tid & 3;    // 0..3  (16-short chunk)
  const size_t rbase = (size_t)(b * 4096 + ch * CHUNK);
  const short* kbase = qkv + (((size_t)(16 + h)) << 19) + rbase * 64 + part * 16;
  const short* vbase = qkv + (((size_t)(32 + h)) << 19) + rbase * 64 + part * 16;

#pragma unroll
  for (int ss = 0; ss < CHUNK; ss += 64) {
    const short* gk = kbase + (size_t)(ss + srl) * 64;
    const short* gv = vbase + (size_t)(ss + srl) * 64;
    short8 k0 = *(const short8*)gk;
    short8 k1 = *(const short8*)(gk + 8);
    short8 v0 = *(const short8*)gv;
    short8 v1 = *(const short8*)(gv + 8);
    const int sidx = ss + srl;
#pragma unroll
    for (int q = 0; q < 8; ++q) {
      kT[part * 16 + q][sidx]     = f2bf(fminf(fmaxf(bf2f(k0[q]) * 0.125f, -1.f), 1.f));
      kT[part * 16 + 8 + q][sidx] = f2bf(fminf(fmaxf(bf2f(k1[q]) * 0.125f, -1.f), 1.f));
      vT[part * 16 + q][sidx]     = v0[q];
      vT[part * 16 + 8 + q][sidx] = v1[q];
    }
  }
  __syncthreads();

  for (int m = 0; m < MD; ++m) {
    if (beta[h * MD + m] == 0.f) continue;

    f32x4 acc[4];
#pragma unroll
    for (int j = 0; j < 4; ++j) acc[j] = (f32x4){0.f, 0.f, 0.f, 0.f};

#pragma unroll 1
    for (int kt = 0; kt < CHUNK / 32; ++kt) {
      const int s0 = kt * 32 + g * 8;
      short8 af;
      if (m == 0) {
#pragma unroll
        for (int q = 0; q < 8; ++q) af[q] = (short)0x3F80;
      } else {
        short8 xs = *(const short8*)&kT[w * 16 + r][s0];
        float Tp[8], Tc[8];
#pragma unroll
        for (int q = 0; q < 8; ++q) { float xv = bf2f(xs[q]); Tp[q] = 1.f; Tc[q] = xv; }
        for (int mm = 1; mm < m; ++mm) {
#pragma unroll
          for (int q = 0; q < 8; ++q) {
            float xv = bf2f(xs[q]);
            float Tn = 2.f * xv * Tc[q] - Tp[q];
            Tp[q] = Tc[q]; Tc[q] = Tn;
          }
        }
#pragma unroll
        for (int q = 0; q < 8; ++q) af[q] = f2bf(Tc[q]);
      }
#pragma unroll
      for (int j = 0; j < 4; ++j) {
        short8 bfg = *(const short8*)&vT[j * 16 + r][s0];
        acc[j] = mfma16(af, bfg, acc[j]);
      }
    }

    short* po = partial + ((size_t)(bh * MD + m) * NCH + ch) * 4096;
#pragma unroll
    for (int j = 0; j < 4; ++j) {
      const int dv = j * 16 + r;
      const int kd = w * 16 + g * 4;
#pragma unroll
      for (int rr = 0; rr < 4; ++rr) po[(size_t)dv * 64 + kd + rr] = f2bf(acc[j][rr]);
    }
  }
}

// ---------------------------------------------------------------------------
// reduce partials (flat, coalesced) -> kvt bf16 [bh][m][dv*64+kd].
// ---------------------------------------------------------------------------
__global__ __launch_bounds__(256) void kv_reduce(const short* __restrict__ partial,
                                                 const float* __restrict__ beta,
                                                 short* __restrict__ kvt) {
  const int m  = blockIdx.x % MD;
  const int bh = blockIdx.x / MD;
  const int h  = bh & 15;
  if (beta[h * MD + m] == 0.f) return;

  const int t = threadIdx.x;
  const short* src = partial + (size_t)(bh * MD + m) * NCH * 4096;
  short* dst = kvt + (size_t)(bh * MD + m) * 4096;

  float s[16];
#pragma unroll
  for (int q = 0; q < 16; ++q) s[q] = 0.f;
#pragma unroll
  for (int c = 0; c < NCH; ++c) {
    short8 a0 = *(const short8*)&src[c * 4096 + t * 16];
    short8 a1 = *(const short8*)&src[c * 4096 + t * 16 + 8];
#pragma unroll
    for (int q = 0; q < 8; ++q) { s[q] += bf2f(a0[q]); s[8 + q] += bf2f(a1[q]); }
  }
  short8 o0, o1;
#pragma unroll
  for (int q = 0; q < 8; ++q) { o0[q] = f2bf(s[q]); o1[q] = f2bf(s[8 + q]); }
  *(short8*)&dst[t * 16]     = o0;
  *(short8*)&dst[t * 16 + 8] = o1;
}

// ---------------------------------------------------------------------------
// attn: per (b,h,256 s-rows). 8-slot kv LDS (66.5KB -> 2 blocks/CU), R14
// loop structure (stage-once, st-outer, per-st acc[4]). Groups of 8 slots;
// groups past the first accumulate through the attn buffer (dead code for
// the real beta: na=5 -> single group).
// ---------------------------------------------------------------------------
__global__ __launch_bounds__(256) void attn_kernel(const short* __restrict__ qkv,
                                                   const float* __restrict__ beta,
                                                   const short* __restrict__ kvt,
                                                   short* __restrict__ attn) {
  const int bid  = blockIdx.x;
  const int bh   = bid >> 4;
  const int sblk = bid & 15;
  const int b    = bh >> 4, h = bh & 15;

  __shared__ short kvT[64][520];   // 8 slots x 64 + 8 pad; 66,560 B

  const int tid  = threadIdx.x;
  const int lane = tid & 63;
  const int w    = tid >> 6;
  const int g    = lane >> 4;
  const int r    = lane & 15;

  float betav[MD];
  int na = 0;
#pragma unroll
  for (int mm = 0; mm < MD; ++mm) {
    betav[mm] = beta[h * MD + mm];
    if (betav[mm] != 0.f) ++na;
  }

  const short* qh = qkv + (((size_t)h) << 19) + (size_t)(b * 4096) * 64;

#pragma unroll 1
  for (int g0 = 0; g0 < na; g0 += 8) {
    if (g0 > 0) __syncthreads();
    // ---- stage this group's kv slices (vectorized, flat) ----
    {
      const int dv  = tid >> 2;
      const int kd0 = (tid & 3) * 16;
      int ord = 0;
#pragma unroll
      for (int mm = 0; mm < MD; ++mm) {
        if (betav[mm] != 0.f) {
          if (ord >= g0 && ord < g0 + 8) {
            const int slot = ord - g0;
            const short* src = kvt + (size_t)(bh * MD + mm) * 4096 + dv * 64 + kd0;
            *(short8*)&kvT[dv][slot * 64 + kd0]     = *(const short8*)src;
            *(short8*)&kvT[dv][slot * 64 + kd0 + 8] = *(const short8*)(src + 8);
          }
          ++ord;
        }
      }
    }
    __syncthreads();

#pragma unroll 1
    for (int st = 0; st < 4; ++st) {
      const int srow = sblk * 256 + w * 64 + st * 16 + r;
      const short* gq = qh + (size_t)srow * 64;
      short8 q0 = *(const short8*)(gq + g * 8);
      short8 q1 = *(const short8*)(gq + 32 + g * 8);
      float x[16];
#pragma unroll
      for (int q = 0; q < 8; ++q) {
        x[q]     = fminf(fmaxf(bf2f(q0[q]) * 0.125f, -1.f), 1.f);
        x[8 + q] = fminf(fmaxf(bf2f(q1[q]) * 0.125f, -1.f), 1.f);
      }
      float Tp[16], Tc[16];
#pragma unroll
      for (int q = 0; q < 16; ++q) { Tp[q] = 1.f; Tc[q] = x[q]; }
      f32x4 acc[4];
#pragma unroll
      for (int j = 0; j < 4; ++j) acc[j] = (f32x4){0.f, 0.f, 0.f, 0.f};

      int ord = 0;
#pragma unroll
      for (int mt = 0; mt < MD; ++mt) {
        if (mt >= 2) {
#pragma unroll
          for (int q = 0; q < 16; ++q) {
            float Tn = 2.f * x[q] * Tc[q] - Tp[q];
            Tp[q] = Tc[q]; Tc[q] = Tn;
          }
        }
        if (betav[mt] != 0.f) {
          if (ord >= g0 && ord < g0 + 8) {
            const int slot = ord - g0;
            const float bm = betav[mt];
            short8 a0, a1;
            if (mt == 0) {
              const short one = f2bf(bm);
#pragma unroll
              for (int q = 0; q < 8; ++q) { a0[q] = one; a1[q] = one; }
            } else {
#pragma unroll
              for (int q = 0; q < 8; ++q) {
                a0[q] = f2bf(bm * Tc[q]);
                a1[q] = f2bf(bm * Tc[8 + q]);
              }
            }
#pragma unroll
            for (int j = 0; j < 4; ++j) {
              short8 b0 = *(const short8*)&kvT[j * 16 + r][slot * 64 + g * 8];
              acc[j] = mfma16(a0, b0, acc[j]);
              short8 b1 = *(const short8*)&kvT[j * 16 + r][slot * 64 + 32 + g * 8];
              acc[j] = mfma16(a1, b1, acc[j]);
            }
          }
          ++ord;
        }
      }

#pragma unroll
      for (int j = 0; j < 4; ++j) {
        const int col = h * 64 + j * 16 + r;
#pragma unroll
        for (int rr = 0; rr < 4; ++rr) {
          const int sr = sblk * 256 + w * 64 + st * 16 + g * 4 + rr;
          short* dp = attn + (size_t)(b * SEQ + sr) * DMODEL + col;
          float v = acc[j][rr];
          if (g0 > 0) v += bf2f(*dp);   // dead for real beta (na=5)
          *dp = f2bf(v);
        }
      }
    }
  }
}

// ---------------------------------------------------------------------------
extern "C" void kernel_launch(void* const* d_in, const int* in_sizes, int n_in,
                              void* d_out, int out_size, void* d_ws, size_t ws_size,
                              hipStream_t stream) {
  const float* x     = (const float*)d_in[0];
  const float* w_in  = (const float*)d_in[1];
  const float* w_out = (const float*)d_in[2];
  const float* beta  = (const float*)d_in[3];
  float* out = (float*)d_out;

  char* ws = (char*)d_ws;
  short* qkv     = (short*)ws;                    // 50,331,648 B (head-major)
  short* kvt     = (short*)(ws + 50331648);       //  2,883,584 B
  short* w_inb   = (short*)(ws + 56098816);       //  6,291,456 B
  short* w_outb  = (short*)(ws + 62390272);       //  2,097,152 B
  char*  regionU = ws + 64487424;                 // xb / partial / attn union
  short* xb      = (short*)regionU;
  short* partial = (short*)regionU;
  short* attn    = (short*)regionU;

  const int Mrows = BATCH * SEQ;  // 8192

  // 0) pre-convert f32 -> bf16 (single fused launch)
  to_bf16_all<<<dim3(12288), dim3(256), 0, stream>>>(x, w_in, w_out, xb, w_inb, w_outb);

  // 1) qkv = x @ w_in^T (head-major out): 32 x 24 = 768 blocks
  gemm256<short, 1><<<dim3((Mrows / 256) * (3 * DMODEL / 128)), dim3(512), 0, stream>>>(
      xb, w_inb, qkv, Mrows, 3 * DMODEL, DMODEL);

  // 2) kv partials over s-chunks, then flat reduce -> kvt
  kv_partial<<<dim3(BATCH * NH * NCH), dim3(256), 0, stream>>>(qkv, beta, partial);
  kv_reduce<<<dim3(BATCH * NH * MD), dim3(256), 0, stream>>>(partial, beta, kvt);

  // 3) attn = sum_m beta_m T_m(q) @ kv_m
  attn_kernel<<<dim3(32 * 16), dim3(256), 0, stream>>>(qkv, beta, kvt, attn);

  // 4) out = attn @ w_out^T: 32 x 8 = 256 blocks
  gemm256<float, 0><<<dim3((Mrows / 256) * (DMODEL / 128)), dim3(512), 0, stream>>>(
      attn, w_outb, out, Mrows, DMODEL, DMODEL);
}